// Round 10
// baseline (2451.012 us; speedup 1.0000x reference)
//
#include <hip/hip_runtime.h>
#include <math.h>

#define NTOT 65536
#define DD 256
#define KK 64

typedef __attribute__((ext_vector_type(8))) short bf16x8;
typedef __attribute__((ext_vector_type(4))) float f32x4;

__device__ __forceinline__ unsigned short f2b(float f) {
    union { float f; unsigned int u; } v; v.f = f;
    unsigned int u = v.u;
    return (unsigned short)((u + 0x7FFFu + ((u >> 16) & 1u)) >> 16);
}

__device__ __forceinline__ uint4 pack8(float4 a, float4 b) {
    uint4 r;
    r.x = (unsigned)f2b(a.x) | ((unsigned)f2b(a.y) << 16);
    r.y = (unsigned)f2b(a.z) | ((unsigned)f2b(a.w) << 16);
    r.z = (unsigned)f2b(b.x) | ((unsigned)f2b(b.y) << 16);
    r.w = (unsigned)f2b(b.z) | ((unsigned)f2b(b.w) << 16);
    return r;
}

// on-the-fly trig row: element e = cos or sin(2*pi*k*(nstart+e)/N), k=r>>1, sin if r odd
__device__ __forceinline__ uint4 trig8(int r, int nstart) {
    const int k = r >> 1;
    const bool odd = (r & 1) != 0;
    float vals[8];
#pragma unroll
    for (int e = 0; e < 8; ++e) {
        const int m = (k * (nstart + e)) & (NTOT - 1);
        const float ang = (float)m * 9.587379924285257e-05f;  // 2*pi/65536
        float s, c;
        __sincosf(ang, &s, &c);
        vals[e] = odd ? s : c;
    }
    uint4 r4;
    r4.x = (unsigned)f2b(vals[0]) | ((unsigned)f2b(vals[1]) << 16);
    r4.y = (unsigned)f2b(vals[2]) | ((unsigned)f2b(vals[3]) << 16);
    r4.z = (unsigned)f2b(vals[4]) | ((unsigned)f2b(vals[5]) << 16);
    r4.w = (unsigned)f2b(vals[6]) | ((unsigned)f2b(vals[7]) << 16);
    return r4;
}

// C/D-layout probe: 1 if acc mapping is (row=lane&15, col=(lane>>4)*4+q),
// 0 if documented (col=lane&15, row=(lane>>4)*4+q). Wave-uniform; robust to
// A/B k-layout (B constant over k -> D[m][n] = n exactly).
__device__ __forceinline__ int cd_probe(int lane) {
    bf16x8 ia, ib;
#pragma unroll
    for (int e = 0; e < 8; ++e) {
        ia[e] = (short)(((lane & 15) == ((lane >> 4) * 8 + e)) ? 0x3F80 : 0);  // I16 (k<16)
        ib[e] = (short)f2b((float)(lane & 15));                               // B[k][n]=n
    }
    f32x4 pacc = (f32x4)0.f;
    pacc = __builtin_amdgcn_mfma_f32_16x16x32_bf16(ia, ib, pacc, 0, 0, 0);
    const float a1 = pacc[1];  // D[m][n]=n
    const bool sw = (fabsf(a1 - (float)(4 * (lane >> 4) + 1)) < 0.25f) &&
                    (fabsf(a1 - (float)(lane & 15)) > 0.25f);
    return (__ballot(sw) != 0ULL) ? 1 : 0;
}

// ---------------- fp32-path ws layout (floats) ----------------
#define CS_OFF    0
#define XRE_OFF   131072
#define XIM_OFF   147456
#define A_OFF     163840
#define BC_OFF    180224
#define PART_OFF  196608
// in-path fallback uses nchunk=128: partials end at 196608+4194304 = 4390912 floats

// ---------------- MFMA-path ws layout (floats) ----------------
#define WT2   0u
#define WPART 4194304u
#define WWT   8388608u
#define WABT  8404992u
#define WXRE  8421376u
#define WXIM  8437760u
#define WA    8454144u
#define WBC   8470528u
#define WFLG  8486912u   // flg[0]=flip_out, flg[1]=flip_dft, flg[2]=gate code
#define WEND  8486928u   // *4 = 33,947,712 bytes (< proven ws >= 34,340,864)

// ============================================================
// shared small kernels (gate: nullptr = always run; else run iff gate[2]!=0)
// ============================================================
__global__ void init_ab(const float* __restrict__ B_low,
                        float* __restrict__ A, float* __restrict__ Bc,
                        const int* __restrict__ gate) {
    if (gate && gate[2] == 0) return;
    const int k = blockIdx.x, f = threadIdx.x;
    const float sc = (k == 0) ? 1.f : 2.f;
    A[k * DD + f]  =  sc * B_low[(k * DD + f) * 2];
    Bc[k * DD + f] = -sc * B_low[(k * DD + f) * 2 + 1];
}

__global__ __launch_bounds__(256) void mode_mix(
        const float* __restrict__ P_low,
        const float* __restrict__ xre, const float* __restrict__ xim,
        float* __restrict__ A, float* __restrict__ Bc,
        const int* __restrict__ gate) {
    if (gate && gate[2] == 0) return;
    const int k = blockIdx.x;
    const int dc = blockIdx.y;  // 0..3
    const int f = threadIdx.x;
    const float2* __restrict__ P2 = (const float2*)P_low;
    float ar = 0.f, ai = 0.f;
#pragma unroll 4
    for (int dd = 0; dd < 64; ++dd) {
        const int d = dc * 64 + dd;
        const float xr = xre[k * DD + d];
        const float xi = xim[k * DD + d];
        const float2 w = P2[(size_t)(k * DD + d) * DD + f];
        ar = fmaf(xr, w.x, ar); ar = fmaf(-xi, w.y, ar);
        ai = fmaf(xr, w.y, ai); ai = fmaf(xi, w.x, ai);
    }
    const float sc = (k == 0) ? 1.f : 2.f;
    atomicAdd(&A[k * DD + f], sc * ar);
    atomicAdd(&Bc[k * DD + f], -sc * ai);
}

// ============================================================
// MFMA path
// ============================================================

// x fp32 [65536][256] -> xbT bf16 [256][65536]  (transpose via padded LDS)
__global__ __launch_bounds__(256) void conv_x(
        const float* __restrict__ x, unsigned short* __restrict__ xbT) {
    __shared__ unsigned short lds[64 * 66];
    const int n0 = blockIdx.x * 64, d0 = blockIdx.y * 64;
    const int t = threadIdx.x;
    const int i = t >> 2, c = t & 3;
#pragma unroll
    for (int q = 0; q < 4; ++q) {
        const float4 v = *(const float4*)&x[(size_t)(n0 + i) * 256 + d0 + c * 16 + q * 4];
        lds[i * 66 + c * 16 + q * 4 + 0] = f2b(v.x);
        lds[i * 66 + c * 16 + q * 4 + 1] = f2b(v.y);
        lds[i * 66 + c * 16 + q * 4 + 2] = f2b(v.z);
        lds[i * 66 + c * 16 + q * 4 + 3] = f2b(v.w);
    }
    __syncthreads();
    const int dd = t >> 2, cc = t & 3;
    unsigned short us[16];
#pragma unroll
    for (int e = 0; e < 16; ++e) us[e] = lds[(cc * 16 + e) * 66 + dd];
    uint4* dst = (uint4*)&xbT[(size_t)(d0 + dd) * 65536 + n0 + cc * 16];
    dst[0] = *(uint4*)&us[0];
    dst[1] = *(uint4*)&us[8];
}

// T2[n][r]: r=2k -> cos(2pi k n/N), r=2k+1 -> +sin(2pi k n/N)
__global__ __launch_bounds__(256) void gen_T2(unsigned short* __restrict__ T2) {
    const int t = threadIdx.x;
    const int n = blockIdx.x * 64 + (t >> 2);
    const int q = t & 3;
    unsigned u[16];
#pragma unroll
    for (int kk = 0; kk < 16; ++kk) {
        const int k = q * 16 + kk;
        const int m = (k * n) & (NTOT - 1);
        const float ang = (float)m * 9.587379924285257e-05f;
        float s, c;
        __sincosf(ang, &s, &c);
        u[kk] = (unsigned)f2b(c) | ((unsigned)f2b(s) << 16);
    }
    uint4* dst = (uint4*)&T2[(size_t)n * 128 + q * 32];
    dst[0] = make_uint4(u[0], u[1], u[2], u[3]);
    dst[1] = make_uint4(u[4], u[5], u[6], u[7]);
    dst[2] = make_uint4(u[8], u[9], u[10], u[11]);
    dst[3] = make_uint4(u[12], u[13], u[14], u[15]);
}

// W [d][f] fp32 -> WT [f][d] bf16
__global__ void conv_w(const float* __restrict__ W, unsigned short* __restrict__ WT) {
    const int d = blockIdx.x, f = threadIdx.x;
    WT[(size_t)f * 256 + d] = f2b(W[(size_t)d * 256 + f]);
}

// A,Bc fp32 [k][f] -> ABT bf16 [f][128]
__global__ void conv_ab(const float* __restrict__ A, const float* __restrict__ Bc,
                        unsigned short* __restrict__ ABT) {
    const int k = blockIdx.x, f = threadIdx.x;
    ABT[(size_t)f * 128 + 2 * k]     = f2b(A[k * DD + f]);
    ABT[(size_t)f * 128 + 2 * k + 1] = f2b(Bc[k * DD + f]);
}

// DFT: part[(ch*2+db)][d 128][r 128] = sum_{n in chunk} xbT[d][n]*trig[r][n]
__global__ __launch_bounds__(256) void dft_gemm(
        const unsigned short* __restrict__ xbT, float* __restrict__ part,
        int* __restrict__ flg) {
    __shared__ unsigned short als[128 * 32];
    __shared__ unsigned short bls[128 * 32];
    const int t = threadIdx.x;
    const int wid = t >> 6, lane = t & 63;
    const int wm = wid >> 1, wn = wid & 1;
    const int db = blockIdx.x, ch = blockIdx.y;
    const int d0 = db * 128;
    const int nbase = ch * 512;

    const int flip = cd_probe(lane);
    if (blockIdx.x == 0 && blockIdx.y == 0 && t == 0) flg[1] = flip;

    f32x4 acc[4][4];
#pragma unroll
    for (int i = 0; i < 4; ++i)
#pragma unroll
        for (int j = 0; j < 4; ++j) acc[i][j] = (f32x4)0.f;

    const int row = t >> 2, cb = (t & 3) * 8;
    uint4 pa0, pa1, pb0, pb1;
    pa0 = *(const uint4*)&xbT[(size_t)(d0 + row) * 65536 + nbase + cb];
    pa1 = *(const uint4*)&xbT[(size_t)(d0 + 64 + row) * 65536 + nbase + cb];
    pb0 = trig8(row, nbase + cb);
    pb1 = trig8(row + 64, nbase + cb);
    for (int s = 0; s < 16; ++s) {
        __syncthreads();
        *(uint4*)&als[row * 32 + cb] = pa0;
        *(uint4*)&als[(64 + row) * 32 + cb] = pa1;
        *(uint4*)&bls[row * 32 + cb] = pb0;
        *(uint4*)&bls[(64 + row) * 32 + cb] = pb1;
        __syncthreads();
        if (s < 15) {
            const int noff = nbase + (s + 1) * 32;
            pa0 = *(const uint4*)&xbT[(size_t)(d0 + row) * 65536 + noff + cb];
            pa1 = *(const uint4*)&xbT[(size_t)(d0 + 64 + row) * 65536 + noff + cb];
            pb0 = trig8(row, noff + cb);
            pb1 = trig8(row + 64, noff + cb);
        }
        bf16x8 af[4], bf[4];
#pragma unroll
        for (int i = 0; i < 4; ++i)
            af[i] = *(const bf16x8*)&als[(wm * 64 + i * 16 + (lane & 15)) * 32 + (lane >> 4) * 8];
#pragma unroll
        for (int j = 0; j < 4; ++j)
            bf[j] = *(const bf16x8*)&bls[(wn * 64 + j * 16 + (lane & 15)) * 32 + (lane >> 4) * 8];
#pragma unroll
        for (int i = 0; i < 4; ++i)
#pragma unroll
            for (int j = 0; j < 4; ++j)
                acc[i][j] = __builtin_amdgcn_mfma_f32_16x16x32_bf16(af[i], bf[j], acc[i][j], 0, 0, 0);
    }
    float* pb = part + (size_t)(ch * 2 + db) * 16384;
#pragma unroll
    for (int i = 0; i < 4; ++i) {
#pragma unroll
        for (int j = 0; j < 4; ++j) {
#pragma unroll
            for (int q = 0; q < 4; ++q) {
                const int r_ = flip ? (lane & 15) : ((lane >> 4) * 4 + q);
                const int c_ = flip ? ((lane >> 4) * 4 + q) : (lane & 15);
                const int dl = wm * 64 + i * 16 + r_;
                const int rl = wn * 64 + j * 16 + c_;
                pb[dl * 128 + rl] = acc[i][j][q];
            }
        }
    }
}

// reduce partials: xre[k][d] = sum/N (r=2k), xim[k][d] = -sum/N (r=2k+1)
__global__ void dft_reduce2(const float* __restrict__ part,
                            float* __restrict__ xre, float* __restrict__ xim) {
    const int idx = blockIdx.x * 256 + threadIdx.x;  // 32768
    const int d = idx >> 7, r = idx & 127;
    const int db = d >> 7, dl = d & 127;
    float s = 0.f;
#pragma unroll 8
    for (int ch = 0; ch < 128; ++ch)
        s += part[(size_t)(ch * 2 + db) * 16384 + dl * 128 + r];
    const int k = r >> 1;
    if ((r & 1) == 0) xre[k * DD + d] = s * (1.f / NTOT);
    else              xim[k * DD + d] = -s * (1.f / NTOT);
}

// fused output: z[n][f] = x[n][:]@W + T2[n][:]@AB + bias; out = sin(0.2 z)
__global__ __launch_bounds__(512) void out_gemm(
        const float* __restrict__ x, const unsigned short* __restrict__ WT,
        const unsigned short* __restrict__ T2, const unsigned short* __restrict__ ABT,
        const float* __restrict__ Bias, float* __restrict__ out,
        int* __restrict__ flg) {
    __shared__ char smem[69632];
    unsigned short* als = (unsigned short*)smem;       // [128][32]
    unsigned short* bls = als + 128 * 32;              // [256][32]
    const int t = threadIdx.x;
    const int wid = t >> 6, lane = t & 63;
    const int wm = wid >> 2, wn = wid & 3;
    const int bn0 = blockIdx.x * 128;

    const int flip = cd_probe(lane);
    if (blockIdx.x == 0 && t == 0) flg[0] = flip;

    f32x4 acc[4][4];
#pragma unroll
    for (int i = 0; i < 4; ++i)
#pragma unroll
        for (int j = 0; j < 4; ++j) acc[i][j] = (f32x4)0.f;

    const int row = t >> 2, cb = (t & 3) * 8;
    uint4 pa, pb0, pb1;
    {
        const float4 v0 = *(const float4*)&x[(size_t)(bn0 + row) * 256 + 0 + cb];
        const float4 v1 = *(const float4*)&x[(size_t)(bn0 + row) * 256 + 0 + cb + 4];
        pa = pack8(v0, v1);
    }
    pb0 = *(const uint4*)&WT[(size_t)row * 256 + 0 + cb];
    pb1 = *(const uint4*)&WT[(size_t)(128 + row) * 256 + 0 + cb];
    for (int s = 0; s < 8; ++s) {
        __syncthreads();
        *(uint4*)&als[row * 32 + cb] = pa;
        *(uint4*)&bls[row * 32 + cb] = pb0;
        *(uint4*)&bls[(128 + row) * 32 + cb] = pb1;
        __syncthreads();
        if (s < 7) {
            const int ko = (s + 1) * 32;
            const float4 v0 = *(const float4*)&x[(size_t)(bn0 + row) * 256 + ko + cb];
            const float4 v1 = *(const float4*)&x[(size_t)(bn0 + row) * 256 + ko + cb + 4];
            pa = pack8(v0, v1);
            pb0 = *(const uint4*)&WT[(size_t)row * 256 + ko + cb];
            pb1 = *(const uint4*)&WT[(size_t)(128 + row) * 256 + ko + cb];
        } else {
            pa  = *(const uint4*)&T2[(size_t)(bn0 + row) * 128 + cb];
            pb0 = *(const uint4*)&ABT[(size_t)row * 128 + cb];
            pb1 = *(const uint4*)&ABT[(size_t)(128 + row) * 128 + cb];
        }
        bf16x8 af[4], bf[4];
#pragma unroll
        for (int i = 0; i < 4; ++i)
            af[i] = *(const bf16x8*)&als[(wm * 64 + i * 16 + (lane & 15)) * 32 + (lane >> 4) * 8];
#pragma unroll
        for (int j = 0; j < 4; ++j)
            bf[j] = *(const bf16x8*)&bls[(wn * 64 + j * 16 + (lane & 15)) * 32 + (lane >> 4) * 8];
#pragma unroll
        for (int i = 0; i < 4; ++i)
#pragma unroll
            for (int j = 0; j < 4; ++j)
                acc[i][j] = __builtin_amdgcn_mfma_f32_16x16x32_bf16(af[i], bf[j], acc[i][j], 0, 0, 0);
    }
    // phase 2: A = T2 (stride 128), B^T = ABT (stride 128), 4 steps
    for (int s = 0; s < 4; ++s) {
        __syncthreads();
        *(uint4*)&als[row * 32 + cb] = pa;
        *(uint4*)&bls[row * 32 + cb] = pb0;
        *(uint4*)&bls[(128 + row) * 32 + cb] = pb1;
        __syncthreads();
        if (s < 3) {
            const int ko = (s + 1) * 32;
            pa  = *(const uint4*)&T2[(size_t)(bn0 + row) * 128 + ko + cb];
            pb0 = *(const uint4*)&ABT[(size_t)row * 128 + ko + cb];
            pb1 = *(const uint4*)&ABT[(size_t)(128 + row) * 128 + ko + cb];
        }
        bf16x8 af[4], bf[4];
#pragma unroll
        for (int i = 0; i < 4; ++i)
            af[i] = *(const bf16x8*)&als[(wm * 64 + i * 16 + (lane & 15)) * 32 + (lane >> 4) * 8];
#pragma unroll
        for (int j = 0; j < 4; ++j)
            bf[j] = *(const bf16x8*)&bls[(wn * 64 + j * 16 + (lane & 15)) * 32 + (lane >> 4) * 8];
#pragma unroll
        for (int i = 0; i < 4; ++i)
#pragma unroll
            for (int j = 0; j < 4; ++j)
                acc[i][j] = __builtin_amdgcn_mfma_f32_16x16x32_bf16(af[i], bf[j], acc[i][j], 0, 0, 0);
    }
    // epilogue: per-wave LDS transpose, bias+sin, store
    __syncthreads();
    float* eps = (float*)smem + wid * 32 * 68;
    const int f_idx = (lane & 15) * 4;
    const float4 bv = *(const float4*)&Bias[wn * 64 + f_idx];
#pragma unroll
    for (int h = 0; h < 2; ++h) {
#pragma unroll
        for (int fm2 = 0; fm2 < 2; ++fm2) {
            const int fm = 2 * h + fm2;
#pragma unroll
            for (int j = 0; j < 4; ++j)
#pragma unroll
                for (int q = 0; q < 4; ++q) {
                    const int r_ = flip ? (lane & 15) : ((lane >> 4) * 4 + q);
                    const int c_ = flip ? ((lane >> 4) * 4 + q) : (lane & 15);
                    eps[(fm2 * 16 + r_) * 68 + j * 16 + c_] = acc[fm][j][q];
                }
        }
#pragma unroll
        for (int rr = 0; rr < 8; ++rr) {
            const int n_idx = rr * 4 + (lane >> 4);
            const float4 v = *(const float4*)&eps[n_idx * 68 + f_idx];
            float4 o;
            o.x = __sinf(0.2f * (v.x + bv.x));
            o.y = __sinf(0.2f * (v.y + bv.y));
            o.z = __sinf(0.2f * (v.z + bv.z));
            o.w = __sinf(0.2f * (v.w + bv.w));
            *(float4*)&out[(size_t)(bn0 + wm * 64 + h * 32 + n_idx) * 256 + wn * 64 + f_idx] = o;
        }
        if (h == 0) __syncthreads();
    }
}

// diagnostic: verify xre/xim (bit 1) and out spot-checks (bit 2).
// Writes gate flg[2] = fb ? (fb | flip0<<2 | flip1<<3) : 0.  Never touches out.
__global__ __launch_bounds__(256) void diag_check(
        const float* __restrict__ x, const float* __restrict__ W,
        const float* __restrict__ Bias,
        const float* __restrict__ xre, const float* __restrict__ xim,
        const float* __restrict__ A, const float* __restrict__ Bc,
        const float* __restrict__ out, int* __restrict__ flg) {
    __shared__ int fb;
    const int t = threadIdx.x;
    if (t == 0) fb = 0;
    __syncthreads();
    const int kk_[4] = {1, 3, 17, 60};
    const int dd_[4] = {0, 7, 100, 255};
    const int w = t >> 6, lane = t & 63;
    const int k = kk_[w], d = dd_[w];
    float sr = 0.f, si = 0.f;
    for (int nn = lane; nn < NTOT; nn += 64) {
        const int m = (k * nn) & (NTOT - 1);
        float s, c;
        sincosf((float)m * 9.587379924285257e-05f, &s, &c);
        const float xv = x[(size_t)nn * DD + d];
        sr = fmaf(xv, c, sr); si = fmaf(xv, s, si);
    }
    for (int off = 32; off; off >>= 1) { sr += __shfl_down(sr, off); si += __shfl_down(si, off); }
    if (lane == 0) {
        const float re = sr * (1.f / NTOT), im = -si * (1.f / NTOT);
        if (fabsf(re - xre[k * DD + d]) > 6e-4f || fabsf(im - xim[k * DD + d]) > 6e-4f)
            atomicOr(&fb, 1);
    }
    __syncthreads();
    if (t < 8) {
        const int ns[8] = {0, 1, 3, 257, 1000, 30000, 65535, 12345};
        const int fs[8] = {0, 5, 100, 17, 255, 128, 7, 200};
        const int n = ns[t], f = fs[t];
        float z = Bias[f];
        for (int d2 = 0; d2 < DD; ++d2)
            z = fmaf(x[(size_t)n * DD + d2], W[(size_t)d2 * DD + f], z);
        for (int k2 = 0; k2 < KK; ++k2) {
            const int m = (k2 * n) & (NTOT - 1);
            float s, c;
            sincosf((float)m * 9.587379924285257e-05f, &s, &c);
            z = fmaf(A[k2 * DD + f], c, z);
            z = fmaf(Bc[k2 * DD + f], s, z);
        }
        const float expct = sinf(0.2f * z);
        if (fabsf(out[(size_t)n * DD + f] - expct) > 6e-3f) atomicOr(&fb, 2);
    }
    __syncthreads();
    if (t == 0)
        flg[2] = fb ? (fb | (flg[0] << 2) | (flg[1] << 3)) : 0;
}

// encodes the fail code as a spin duration (~50us per code unit), readable in rocprof
__global__ void spin_encode(const int* __restrict__ flg, float* __restrict__ sink) {
    const int code = flg[2];
    if (code == 0) return;
    float v = 1.0f + (float)threadIdx.x;
    const int iters = code * 30000;
    for (int i = 0; i < iters; ++i)
        v = fmaf(v, 0.99999f, 1e-9f);
    if (v < 0.f) sink[0] = v;  // never true; keeps the chain live
}

// ============================================================
// fp32 path (known-good round-2 kernels; gated when used as fallback)
// ============================================================
__global__ void gen_cs(float2* __restrict__ cs, const int* __restrict__ gate) {
    if (gate && gate[2] == 0) return;
    const int m = blockIdx.x * 256 + threadIdx.x;
    const float ang = (float)m * 9.587379924285257e-05f;
    float s, c;
    sincosf(ang, &s, &c);
    cs[m] = make_float2(c, s);
}

__global__ __launch_bounds__(256) void dft_partial(
        const float* __restrict__ x, const float2* __restrict__ cs,
        float2* __restrict__ part, int clen, const int* __restrict__ gate) {
    if (gate && gate[2] == 0) return;
    const int chunk = blockIdx.x;
    const int kb = blockIdx.y * 32;
    const int d = threadIdx.x;
    float ar[32], ai[32];
#pragma unroll
    for (int i = 0; i < 32; ++i) { ar[i] = 0.f; ai[i] = 0.f; }
    const int n0 = chunk * clen;
    for (int nn = 0; nn < clen; ++nn) {
        const int n = n0 + nn;
        const float xv = x[(size_t)n * DD + d];
#pragma unroll
        for (int kk = 0; kk < 32; ++kk) {
            const int m = ((kb + kk) * n) & (NTOT - 1);
            const float2 t = cs[m];
            ar[kk] = fmaf(xv, t.x, ar[kk]);
            ai[kk] = fmaf(-xv, t.y, ai[kk]);
        }
    }
#pragma unroll
    for (int kk = 0; kk < 32; ++kk)
        part[(size_t)(chunk * KK + kb + kk) * DD + d] = make_float2(ar[kk], ai[kk]);
}

__global__ void dft_reduce(const float2* __restrict__ part,
                           float* __restrict__ xre, float* __restrict__ xim,
                           int nchunk, const int* __restrict__ gate) {
    if (gate && gate[2] == 0) return;
    const int k = blockIdx.x;
    const int d = blockIdx.y * 64 + threadIdx.x;
    float sr = 0.f, si = 0.f;
#pragma unroll 8
    for (int c = 0; c < nchunk; ++c) {
        const float2 p = part[(size_t)(c * KK + k) * DD + d];
        sr += p.x; si += p.y;
    }
    xre[k * DD + d] = sr * (1.f / NTOT);
    xim[k * DD + d] = si * (1.f / NTOT);
}

__global__ __launch_bounds__(256) void fno_out(
        const float* __restrict__ x, const float* __restrict__ W,
        const float* __restrict__ Bias, const float2* __restrict__ cs,
        const float* __restrict__ A, const float* __restrict__ Bc,
        float* __restrict__ out, const int* __restrict__ gate) {
    if (gate && gate[2] == 0) return;
    const int tf = threadIdx.x & 31;
    const int tn = threadIdx.x >> 5;
    const int f0 = tf * 8;
    const int n0 = blockIdx.x * 64 + tn * 8;
    float acc[8][8];
#pragma unroll
    for (int i = 0; i < 8; ++i)
#pragma unroll
        for (int j = 0; j < 8; ++j) acc[i][j] = 0.f;
    const float4* __restrict__ W4 = (const float4*)W;
    for (int d = 0; d < DD; ++d) {
        float xv[8];
#pragma unroll
        for (int i = 0; i < 8; ++i) xv[i] = x[(size_t)(n0 + i) * DD + d];
        const float4 wa = W4[(d * DD + f0) >> 2];
        const float4 wb = W4[((d * DD + f0) >> 2) + 1];
        const float w[8] = {wa.x, wa.y, wa.z, wa.w, wb.x, wb.y, wb.z, wb.w};
#pragma unroll
        for (int i = 0; i < 8; ++i)
#pragma unroll
            for (int j = 0; j < 8; ++j) acc[i][j] = fmaf(xv[i], w[j], acc[i][j]);
    }
    const float4* __restrict__ A4 = (const float4*)A;
    const float4* __restrict__ B4 = (const float4*)Bc;
#pragma unroll 1
    for (int k = 0; k < KK; ++k) {
        const float4 a0 = A4[(k * DD + f0) >> 2];
        const float4 a1 = A4[((k * DD + f0) >> 2) + 1];
        const float4 b0 = B4[(k * DD + f0) >> 2];
        const float4 b1 = B4[((k * DD + f0) >> 2) + 1];
        const float av[8] = {a0.x, a0.y, a0.z, a0.w, a1.x, a1.y, a1.z, a1.w};
        const float bv[8] = {b0.x, b0.y, b0.z, b0.w, b1.x, b1.y, b1.z, b1.w};
#pragma unroll
        for (int i = 0; i < 8; ++i) {
            const int m = (k * (n0 + i)) & (NTOT - 1);
            const float2 tt = cs[m];
#pragma unroll
            for (int j = 0; j < 8; ++j) {
                acc[i][j] = fmaf(tt.x, av[j], acc[i][j]);
                acc[i][j] = fmaf(tt.y, bv[j], acc[i][j]);
            }
        }
    }
    const float4 bia = ((const float4*)Bias)[f0 >> 2];
    const float4 bib = ((const float4*)Bias)[(f0 >> 2) + 1];
    const float bi[8] = {bia.x, bia.y, bia.z, bia.w, bib.x, bib.y, bib.z, bib.w};
#pragma unroll
    for (int i = 0; i < 8; ++i) {
        float o[8];
#pragma unroll
        for (int j = 0; j < 8; ++j) o[j] = __sinf(0.2f * (acc[i][j] + bi[j]));
        float4* op = (float4*)(out + (size_t)(n0 + i) * DD + f0);
        op[0] = make_float4(o[0], o[1], o[2], o[3]);
        op[1] = make_float4(o[4], o[5], o[6], o[7]);
    }
}

// ============================================================
extern "C" void kernel_launch(void* const* d_in, const int* in_sizes, int n_in,
                              void* d_out, int out_size, void* d_ws, size_t ws_size,
                              hipStream_t stream) {
    const float* x     = (const float*)d_in[0];
    const float* P_low = (const float*)d_in[1];
    const float* B_low = (const float*)d_in[2];
    const float* W     = (const float*)d_in[3];
    const float* Bias  = (const float*)d_in[4];
    float* out = (float*)d_out;
    float* ws  = (float*)d_ws;

    if (ws_size >= (size_t)WEND * 4u) {
        // ---- MFMA path ----
        unsigned short* xbT = (unsigned short*)d_out;   // scratch in d_out; overwritten by out_gemm
        unsigned short* T2  = (unsigned short*)(ws + WT2);
        float*          part = ws + WPART;
        unsigned short* WT  = (unsigned short*)(ws + WWT);
        unsigned short* ABT = (unsigned short*)(ws + WABT);
        float* xre = ws + WXRE;
        float* xim = ws + WXIM;
        float* A   = ws + WA;
        float* Bc  = ws + WBC;
        int*   flg = (int*)(ws + WFLG);

        conv_x<<<dim3(1024, 4), 256, 0, stream>>>(x, xbT);
        gen_T2<<<1024, 256, 0, stream>>>(T2);
        conv_w<<<256, 256, 0, stream>>>(W, WT);
        dft_gemm<<<dim3(2, 128), 256, 0, stream>>>(xbT, part, flg);
        dft_reduce2<<<128, 256, 0, stream>>>(part, xre, xim);
        init_ab<<<KK, DD, 0, stream>>>(B_low, A, Bc, nullptr);
        mode_mix<<<dim3(KK, 4), 256, 0, stream>>>(P_low, xre, xim, A, Bc, nullptr);
        conv_ab<<<KK, DD, 0, stream>>>(A, Bc, ABT);
        out_gemm<<<512, 512, 0, stream>>>(x, WT, T2, ABT, Bias, out, flg);
        diag_check<<<1, 256, 0, stream>>>(x, W, Bias, xre, xim, A, Bc, out, flg);

        // ---- gated fp32 fallback (runs only if diag failed; nchunk=128 keeps
        //      partials below flg). Guarantees a correct output either way. ----
        float2* cs2   = (float2*)(ws + CS_OFF);
        float*  xre2  = ws + XRE_OFF;
        float*  xim2  = ws + XIM_OFF;
        float*  A2    = ws + A_OFF;
        float*  Bc2   = ws + BC_OFF;
        float2* part2 = (float2*)(ws + PART_OFF);
        gen_cs<<<NTOT / 256, 256, 0, stream>>>(cs2, flg);
        init_ab<<<KK, DD, 0, stream>>>(B_low, A2, Bc2, flg);
        dft_partial<<<dim3(128, 2), 256, 0, stream>>>(x, cs2, part2, 512, flg);
        dft_reduce<<<dim3(KK, 4), 64, 0, stream>>>(part2, xre2, xim2, 128, flg);
        mode_mix<<<dim3(KK, 4), 256, 0, stream>>>(P_low, xre2, xim2, A2, Bc2, flg);
        fno_out<<<NTOT / 64, 256, 0, stream>>>(x, W, Bias, cs2, A2, Bc2, out, flg);
        spin_encode<<<1, 64, 0, stream>>>(flg, ws + WPART);
    } else {
        // ---- pure fp32 path (ws too small for MFMA buffers) ----
        float2* cs   = (float2*)(ws + CS_OFF);
        float*  xre  = ws + XRE_OFF;
        float*  xim  = ws + XIM_OFF;
        float*  A    = ws + A_OFF;
        float*  Bc   = ws + BC_OFF;
        float2* part = (float2*)(ws + PART_OFF);
        int nchunk = 256;
        while ((size_t)(PART_OFF + (size_t)nchunk * KK * DD * 2) * 4 > ws_size && nchunk > 32)
            nchunk >>= 1;
        const int clen = NTOT / nchunk;
        gen_cs<<<NTOT / 256, 256, 0, stream>>>(cs, nullptr);
        init_ab<<<KK, DD, 0, stream>>>(B_low, A, Bc, nullptr);
        dft_partial<<<dim3(nchunk, 2), 256, 0, stream>>>(x, cs, part, clen, nullptr);
        dft_reduce<<<dim3(KK, 4), 64, 0, stream>>>(part, xre, xim, nchunk, nullptr);
        mode_mix<<<dim3(KK, 4), 256, 0, stream>>>(P_low, xre, xim, A, Bc, nullptr);
        fno_out<<<NTOT / 64, 256, 0, stream>>>(x, W, Bias, cs, A, Bc, out, nullptr);
    }
}